// Round 3
// baseline (621.443 us; speedup 1.0000x reference)
//
#include <hip/hip_runtime.h>
#include <hip/hip_bf16.h>

using f32x4 = __attribute__((ext_vector_type(4))) float;
using bf16x8 = __attribute__((ext_vector_type(8))) short;

#define DEVI __device__ __forceinline__

// compiler-lowered conversions (v_cvt_pk_bf16_f32) — m240: don't hand-roll
DEVI short f2bf(float f) { __hip_bfloat16 h = __float2bfloat16(f); return *reinterpret_cast<short*>(&h); }
DEVI unsigned int pk2(float a, float b) {
    float2 t; t.x = a; t.y = b;
    __hip_bfloat162 h = __float22bfloat162_rn(t);
    return *reinterpret_cast<unsigned int*>(&h);
}
DEVI float bf2f(unsigned short s) { unsigned int u = ((unsigned int)s) << 16; return __uint_as_float(u); }

constexpr int NB = 8192;   // windows
constexpr int NT = 49;     // tokens per window
constexpr int CD = 128;    // channels
constexpr float SCALE = 0.17677669529663687f; // 32^-0.5
constexpr float LOG2E = 1.4426950408889634f;

// LDS pool (shorts)
constexpr int QK_STRIDE = 72;                 // 144 B rows, 16B-aligned, bank-spread
constexpr int QK_HEAD   = 64 * QK_STRIDE;     // per head: q cols 0..31, k cols 32..63; later P [64][64]
constexpr int VT_BASE   = 4 * QK_HEAD;        // 18432 shorts
constexpr int POOL_SH   = VT_BASE + 4 * 32 * 64;  // 26624 shorts = 53248 B -> 3 blocks/CU

// ws layout (bytes)
constexpr size_t WS_QKVWT  = 0;       // 384*128 bf16
constexpr size_t WS_PROJWT = 98304;   // 128*128 bf16
constexpr size_t WS_BIAS   = 131072;  // 4*2401 bf16 gathered rel bias [h][q][k]

__global__ __launch_bounds__(256) void prep_kernel(
    const float* __restrict__ qkv_w, const float* __restrict__ proj_w,
    const float* __restrict__ rbt, const int* __restrict__ rel_index,
    short* __restrict__ qkvwT, short* __restrict__ projwT, unsigned short* __restrict__ biasBf)
{
    int i = blockIdx.x * 256 + threadIdx.x;
    if (i < 384 * 128) { int j = i >> 7, k = i & 127; qkvwT[i] = f2bf(qkv_w[k * 384 + j]); }
    if (i < 128 * 128) { int j = i >> 7, k = i & 127; projwT[i] = f2bf(proj_w[k * 128 + j]); }
    if (i < 4 * NT * NT) { int h = i / (NT * NT); int t = i % (NT * NT); biasBf[i] = (unsigned short)f2bf(rbt[rel_index[t] * 4 + h]); }
}

// swizzled index into the [64][128] bf16 o tile
DEVI int swz128(int row, int col) { return row * 128 + (col ^ ((row & 7) << 3)); }

__global__ __launch_bounds__(512, 6) void winattn_kernel(
    const float* __restrict__ x, const float* __restrict__ mask,
    const float* __restrict__ qkv_b, const float* __restrict__ proj_b,
    const short* __restrict__ qkvwT, const short* __restrict__ projwT,
    const unsigned short* __restrict__ biasBf, float* __restrict__ out)
{
    __shared__ short pool[POOL_SH];
    short* qk = pool;            // [4 heads][64][72]
    short* vT = pool + VT_BASE;  // [4 heads][32][64] XOR-swizzled; later o [64][128] swizzled

    const int b = blockIdx.x;
    const int tid = threadIdx.x;
    const int w = tid >> 6;      // wave 0..7
    const int lane = tid & 63;
    const int lr = lane & 15;
    const int lg = lane >> 4;
    const int wr = w >> 1;       // row-tile / head owner
    const int wh = w & 1;        // half-split selector

    // ---- A-fragments straight from global (no LDS roundtrip) ----
    bf16x8 a[4];
    {
        const int arow = 16 * wr + lr;
        const bool avalid = arow < NT;
        const float* xrow = x + (long)b * NT * CD + arow * CD;
#pragma unroll
        for (int kt = 0; kt < 4; ++kt) {
            float4 v0 = {0.f, 0.f, 0.f, 0.f}, v1 = {0.f, 0.f, 0.f, 0.f};
            if (avalid) {
                const float4* p = reinterpret_cast<const float4*>(xrow + kt * 32 + lg * 8);
                v0 = p[0]; v1 = p[1];
            }
            union { unsigned int u[4]; bf16x8 v; } cv;
            cv.u[0] = pk2(v0.x, v0.y); cv.u[1] = pk2(v0.z, v0.w);
            cv.u[2] = pk2(v1.x, v1.y); cv.u[3] = pk2(v1.z, v1.w);
            a[kt] = cv.v;
        }
    }

    // ---- QKV GEMM: wave -> rows 16*wr..+16, nt half ----
    {
        int nt0 = wh * 12;
#pragma unroll
        for (int i = 0; i < 12; ++i) {
            int nt = nt0 + i;
            f32x4 acc = {0.f, 0.f, 0.f, 0.f};
#pragma unroll
            for (int kt = 0; kt < 4; ++kt) {
                bf16x8 bb = *reinterpret_cast<const bf16x8*>(&qkvwT[(nt * 16 + lr) * 128 + kt * 32 + lg * 8]);
                acc = __builtin_amdgcn_mfma_f32_16x16x32_bf16(a[kt], bb, acc, 0, 0, 0);
            }
            int s = nt >> 3;            // 0=q 1=k 2=v (uniform per nt)
            int h = (nt >> 1) & 3;      // head (uniform per nt)
            int d = (nt & 1) * 16 + lr; // head dim
            float bias = qkv_b[nt * 16 + lr];
#pragma unroll
            for (int r = 0; r < 4; ++r) {
                int row = 16 * wr + 4 * lg + r;
                float vv = acc[r] + bias;
                if (s == 0)      qk[h * QK_HEAD + row * QK_STRIDE + d] = f2bf(vv * SCALE);
                else if (s == 1) qk[h * QK_HEAD + row * QK_STRIDE + 32 + d] = f2bf(vv);
                else             vT[h * 2048 + d * 64 + (row ^ ((d & 7) << 3))] = f2bf(vv);
            }
        }
    }
    __syncthreads();   // #1: q/k/v visible

    // ---- attention: wave -> head wr, query tiles mt0..mt0+1 ----
    {
        const int h = wr;
        const int mt0 = wh * 2;
        short* qh = qk + h * QK_HEAD;

        bf16x8 qa[2], kb[4];
#pragma unroll
        for (int t = 0; t < 2; ++t)
            qa[t] = *reinterpret_cast<const bf16x8*>(&qh[(16 * (mt0 + t) + lr) * QK_STRIDE + lg * 8]);
#pragma unroll
        for (int t = 0; t < 4; ++t)
            kb[t] = *reinterpret_cast<const bf16x8*>(&qh[(16 * t + lr) * QK_STRIDE + 32 + lg * 8]);
        __syncthreads();   // #2: all q/k frag loads done before any P overwrite

        const float* maskb = mask + (long)b * NT * NT;
        const unsigned short* biash = biasBf + h * NT * NT;

        f32x4 oacc[2][2];
#pragma unroll
        for (int mt2 = 0; mt2 < 2; ++mt2)
#pragma unroll
            for (int nt = 0; nt < 2; ++nt)
                oacc[mt2][nt] = f32x4{0.f, 0.f, 0.f, 0.f};

#pragma unroll
        for (int mt2 = 0; mt2 < 2; ++mt2) {
            const int mt = mt0 + mt2;

            // mask prefetch for this half (hides HBM latency under the MFMAs below)
            float mreg[4][4];
#pragma unroll
            for (int r = 0; r < 4; ++r) {
                int R = 16 * mt + 4 * lg + r;
#pragma unroll
                for (int ct = 0; ct < 4; ++ct) {
                    int c = 16 * ct + lr;
                    bool ok = (R < NT) && (c < NT);
                    mreg[r][ct] = ok ? maskb[R * NT + c] : 0.f;
                }
            }

            f32x4 sacc[4];
#pragma unroll
            for (int ct = 0; ct < 4; ++ct) {
                f32x4 z = {0.f, 0.f, 0.f, 0.f};
                sacc[ct] = __builtin_amdgcn_mfma_f32_16x16x32_bf16(qa[mt2], kb[ct], z, 0, 0, 0);
            }

            // softmax without max-subtraction (scores bounded ~|10|; exact math, fp32-safe)
#pragma unroll
            for (int r = 0; r < 4; ++r) {
                int R = 16 * mt + 4 * lg + r;
                bool rv = R < NT;
                float e[4];
                float sum;
#pragma unroll
                for (int ct = 0; ct < 4; ++ct) {
                    int c = 16 * ct + lr;
                    bool cvalid = c < NT;
                    float bval = (rv && cvalid) ? bf2f(biash[R * NT + c]) : 0.f;
                    float sv = sacc[ct][r] + mreg[r][ct] + bval;
                    e[ct] = cvalid ? exp2f(sv * LOG2E) : 0.f;
                }
                sum = (e[0] + e[1]) + (e[2] + e[3]);
                sum += __shfl_xor(sum, 1);
                sum += __shfl_xor(sum, 2);
                sum += __shfl_xor(sum, 4);
                sum += __shfl_xor(sum, 8);
                float inv = 1.0f / sum;
#pragma unroll
                for (int ct = 0; ct < 4; ++ct)
                    qh[R * QK_STRIDE + 16 * ct + lr] = f2bf(e[ct] * inv);
            }

            // PV for this half (own-wave P rows; compiler orders LDS write->read)
            bf16x8 pa0 = *reinterpret_cast<const bf16x8*>(&qh[(16 * mt + lr) * QK_STRIDE + lg * 8]);
            bf16x8 pa1 = *reinterpret_cast<const bf16x8*>(&qh[(16 * mt + lr) * QK_STRIDE + 32 + lg * 8]);
#pragma unroll
            for (int nt = 0; nt < 2; ++nt) {
                int dl = 16 * nt + lr;
                bf16x8 vb0 = *reinterpret_cast<const bf16x8*>(
                    &vT[h * 2048 + dl * 64 + ((lg * 8) ^ ((dl & 7) << 3))]);
                bf16x8 vb1 = *reinterpret_cast<const bf16x8*>(
                    &vT[h * 2048 + dl * 64 + ((32 + lg * 8) ^ ((dl & 7) << 3))]);
                oacc[mt2][nt] = __builtin_amdgcn_mfma_f32_16x16x32_bf16(pa0, vb0, oacc[mt2][nt], 0, 0, 0);
                oacc[mt2][nt] = __builtin_amdgcn_mfma_f32_16x16x32_bf16(pa1, vb1, oacc[mt2][nt], 0, 0, 0);
            }
        }
        __syncthreads();   // #3: all PV vT reads done; vT region becomes o

        short* o = vT;     // [64][128] swizzled
#pragma unroll
        for (int mt2 = 0; mt2 < 2; ++mt2)
#pragma unroll
            for (int nt = 0; nt < 2; ++nt)
#pragma unroll
                for (int r = 0; r < 4; ++r) {
                    int row = 16 * (mt0 + mt2) + 4 * lg + r;
                    int col = 32 * h + 16 * nt + lr;
                    o[swz128(row, col)] = f2bf(oacc[mt2][nt][r]);
                }
    }
    __syncthreads();   // #4: o visible

    // ---- proj: wave -> rows 16*wr..+16, col tiles wh*4..+4 ----
    {
        const short* o = vT;
        bf16x8 ao[4];
#pragma unroll
        for (int kt = 0; kt < 4; ++kt)
            ao[kt] = *reinterpret_cast<const bf16x8*>(&o[swz128(16 * wr + lr, kt * 32 + lg * 8)]);
        int n0 = wh * 4;
#pragma unroll
        for (int i = 0; i < 4; ++i) {
            int nt = n0 + i;
            f32x4 acc = {0.f, 0.f, 0.f, 0.f};
#pragma unroll
            for (int kt = 0; kt < 4; ++kt) {
                bf16x8 bb = *reinterpret_cast<const bf16x8*>(&projwT[(nt * 16 + lr) * 128 + kt * 32 + lg * 8]);
                acc = __builtin_amdgcn_mfma_f32_16x16x32_bf16(ao[kt], bb, acc, 0, 0, 0);
            }
            int col = nt * 16 + lr;
            float pb = proj_b[col];
#pragma unroll
            for (int r = 0; r < 4; ++r) {
                int row = 16 * wr + 4 * lg + r;
                if (row < NT)
                    out[((long)b * NT + row) * CD + col] = acc[r] + pb;
            }
        }
    }
}

extern "C" void kernel_launch(void* const* d_in, const int* in_sizes, int n_in,
                              void* d_out, int out_size, void* d_ws, size_t ws_size,
                              hipStream_t stream) {
    const float* x      = (const float*)d_in[0];
    const float* mask   = (const float*)d_in[1];
    const float* qkv_w  = (const float*)d_in[2];
    const float* qkv_b  = (const float*)d_in[3];
    const float* rbt    = (const float*)d_in[4];
    const float* proj_w = (const float*)d_in[5];
    const float* proj_b = (const float*)d_in[6];
    const int*   ridx   = (const int*)d_in[7];
    float* out = (float*)d_out;

    char* ws = (char*)d_ws;
    short* qkvwT  = (short*)(ws + WS_QKVWT);
    short* projwT = (short*)(ws + WS_PROJWT);
    unsigned short* biasBf = (unsigned short*)(ws + WS_BIAS);

    prep_kernel<<<192, 256, 0, stream>>>(qkv_w, proj_w, rbt, ridx, qkvwT, projwT, biasBf);
    winattn_kernel<<<NB, 512, 0, stream>>>(x, mask, qkv_b, proj_b, qkvwT, projwT, biasBf, out);
}